// Round 3
// baseline (87.056 us; speedup 1.0000x reference)
//
#include <hip/hip_runtime.h>
#include <math.h>

#define N_PTS   2048
#define BLOCK   256
#define NQ      8      // queries per thread -> 2048 queries per block (whole cloud)
#define SLAB    128    // candidates staged per block
#define NSLAB   (N_PTS / SLAB)   // 16

// Grid: (32 bs, 2 dir, 16 slab) = 1024 blocks, 256 threads.
// Each block: stage 128 candidates as (x,y,z,|q|^2) in LDS; each thread tracks
// running min of (|q|^2 - 2 p.q) for its 8 query points, 2 candidates per
// iteration (3 FMA x2 + v_min3), then STORES the partial d^2 = p2 + best to a
// per-slab private slice of ws. No atomics, no ws init needed.
__global__ __launch_bounds__(BLOCK) void chamfer_min_kernel(
    const float* __restrict__ pred,
    const float* __restrict__ tgt,
    float* __restrict__ ws)
{
    __shared__ float4 sh[SLAB];

    const int bs   = blockIdx.x;   // 0..31
    const int dir  = blockIdx.y;   // 0..1
    const int slab = blockIdx.z;   // 0..15
    const int tid  = threadIdx.x;

    const float* Abase = (dir ? tgt : pred) + (size_t)bs * N_PTS * 3;  // queries
    const float* Bbase = (dir ? pred : tgt) + (size_t)bs * N_PTS * 3;  // candidates

    if (tid < SLAB) {
        const int j = slab * SLAB + tid;
        const float x = Bbase[3 * j + 0];
        const float y = Bbase[3 * j + 1];
        const float z = Bbase[3 * j + 2];
        sh[tid] = make_float4(x, y, z, x * x + y * y + z * z);
    }
    __syncthreads();

    float nx[NQ], ny[NQ], nz[NQ], p2[NQ], best[NQ];
    #pragma unroll
    for (int k = 0; k < NQ; ++k) {
        const int q = tid + BLOCK * k;
        const float px = Abase[3 * q + 0];
        const float py = Abase[3 * q + 1];
        const float pz = Abase[3 * q + 2];
        nx[k] = -2.0f * px;
        ny[k] = -2.0f * py;
        nz[k] = -2.0f * pz;
        p2[k] = px * px + py * py + pz * pz;
        best[k] = 3.4e38f;
    }

    // Hot loop: 2 candidates/iter; min(best, min(v0,v1)) -> v_min3_f32.
    #pragma unroll 2
    for (int j = 0; j < SLAB; j += 2) {
        const float4 t0 = sh[j];
        const float4 t1 = sh[j + 1];
        #pragma unroll
        for (int k = 0; k < NQ; ++k) {
            const float v0 = fmaf(nx[k], t0.x,
                             fmaf(ny[k], t0.y,
                             fmaf(nz[k], t0.z, t0.w)));
            const float v1 = fmaf(nx[k], t1.x,
                             fmaf(ny[k], t1.y,
                             fmaf(nz[k], t1.z, t1.w)));
            best[k] = fminf(best[k], fminf(v0, v1));
        }
    }

    // Store per-slab partial d^2 (may be slightly negative; clamp at finalize).
    // Layout: ws[((dir*NSLAB + slab)*32 + bs)*N_PTS + q] -> coalesced stores.
    float* dst = ws + ((size_t)(dir * NSLAB + slab) * 32 + bs) * N_PTS;
    #pragma unroll
    for (int k = 0; k < NQ; ++k)
        dst[tid + BLOCK * k] = p2[k] + best[k];
}

// For each of 131072 (dir,bs,q) points: min over 16 slab partials, clamp,
// sqrt, block-reduce, one atomicAdd. Grid: 512 blocks x 256 threads.
__global__ __launch_bounds__(BLOCK) void chamfer_finalize_kernel(
    const float* __restrict__ ws,
    float* __restrict__ out)
{
    __shared__ float red[BLOCK / 64];
    const int i = blockIdx.x * BLOCK + threadIdx.x;   // 0..131071
    const int dir = i >> 16;                          // 0..1
    const int bsq = i & 0xFFFF;                       // (bs,q) combined: bs*2048+q

    float m = 3.4e38f;
    #pragma unroll
    for (int s = 0; s < NSLAB; ++s) {
        // ws[((dir*16+s)*32+bs)*2048 + q] == ws[(dir*16+s)*65536 + bsq]
        m = fminf(m, ws[(size_t)(dir * NSLAB + s) * 65536 + bsq]);
    }
    float d = sqrtf(fmaxf(m, 0.0f));

    for (int off = 32; off > 0; off >>= 1)
        d += __shfl_down(d, off, 64);
    const int tid = threadIdx.x;
    if ((tid & 63) == 0) red[tid >> 6] = d;
    __syncthreads();
    if (tid == 0) {
        const float blk = red[0] + red[1] + red[2] + red[3];
        atomicAdd(out, blk * (1.0f / 65536.0f));  // 1/(B*S*N), N==M
    }
}

extern "C" void kernel_launch(void* const* d_in, const int* in_sizes, int n_in,
                              void* d_out, int out_size, void* d_ws, size_t ws_size,
                              hipStream_t stream) {
    const float* pred = (const float*)d_in[0];
    const float* tgt  = (const float*)d_in[1];
    float* out = (float*)d_out;
    float* ws = (float*)d_ws;   // 2*16*32*2048 floats = 8 MB partial mins

    hipMemsetAsync(out, 0, sizeof(float), stream);

    dim3 grid(32, 2, NSLAB);
    chamfer_min_kernel<<<grid, BLOCK, 0, stream>>>(pred, tgt, ws);

    chamfer_finalize_kernel<<<131072 / BLOCK, BLOCK, 0, stream>>>(ws, out);
}